// Round 1
// 203.085 us; speedup vs baseline: 1.0490x; 1.0490x over previous
//
#include <hip/hip_runtime.h>
#include <math.h>

// NormalMixtureEM: B=16384 rows, L=512, K=4, 5 EM iters. One wave per row.
// R5 (VALU-issue reduction; kernel was 86% VALUBusy, 0% MFMA, 22% HBM):
//  - Ratio softmax: divide by component 3 -> 3 exp2 + 1 rcp per sample
//    (was 4+1), lm as delta-quadratic (6 fmas, was 8). g3 = inv.
//  - float2 packed math everywhere in the inner loop (v_pk_fma_f32 etc.):
//    samples processed in pairs, halving full-rate issue slots if packed
//    fp32 is full-rate on gfx950 (neutral if split).
//  - wred3: inline-asm interleaved v_add_f32_dpp reduction of 3 moments at
//    once (18 instrs, no mov+add pairs, no per-step hazard nops; round-robin
//    keeps same-reg DPP reads >=3 instrs apart; s_nop guards at the seams).
//  - dwordx4 loads of windows/weights_param (sample->lane mapping changed to
//    l = 256*(p>>1) + 4*lane + 2*(p&1) + h; reductions are mapping-invariant).
//  - Iteration-invariant totals W{0,1,2} still derive component 3's moments.

constexpr int Bn = 16384;
constexpr int Ln = 512;
constexpr int Kn = 4;
constexpr int NITER = 5;
constexpr float EPSf = 1e-8f;
constexpr float NOISEf = 0.01f;
constexpr float LOG2E = 1.4426950408889634f;

typedef float v2f __attribute__((ext_vector_type(2)));

__device__ __forceinline__ float frcp(float v) { return __builtin_amdgcn_rcpf(v); }
__device__ __forceinline__ float fexp2(float v) { return __builtin_amdgcn_exp2f(v); }
__device__ __forceinline__ v2f vfma(v2f a, v2f b, v2f c) {
    return __builtin_elementwise_fma(a, b, c);
}
__device__ __forceinline__ v2f v2(float a, float b) { v2f r; r.x = a; r.y = b; return r; }
__device__ __forceinline__ v2f v2u(float a) { v2f r; r.x = a; r.y = a; return r; }

// Three interleaved full-wave sums via DPP adds. Lane 63 holds each total.
// Round-robin over %0,%1,%2 keeps dependent same-register DPP reads 3 instrs
// apart (>= 2 wait states); s_nop 1 covers the VALU->DPP entry hazard and the
// (asm)VALU->v_readlane exit hazard.
#define WRED3_STEP(ctrl) \
    "v_add_f32_dpp %0, %0, %0 " ctrl " row_mask:0xf bank_mask:0xf bound_ctrl:0\n\t" \
    "v_add_f32_dpp %1, %1, %1 " ctrl " row_mask:0xf bank_mask:0xf bound_ctrl:0\n\t" \
    "v_add_f32_dpp %2, %2, %2 " ctrl " row_mask:0xf bank_mask:0xf bound_ctrl:0\n\t"

__device__ __forceinline__ void wred3(float& a, float& b, float& c) {
    asm volatile(
        "s_nop 1\n\t"
        WRED3_STEP("row_shr:1")
        WRED3_STEP("row_shr:2")
        WRED3_STEP("row_shr:4")
        WRED3_STEP("row_shr:8")
        WRED3_STEP("row_bcast:15")
        WRED3_STEP("row_bcast:31")
        "s_nop 1"
        : "+v"(a), "+v"(b), "+v"(c));
}

__device__ __forceinline__ float lane63(float v) {
    return __int_as_float(__builtin_amdgcn_readlane(__float_as_int(v), 63));
}

struct RowState {
    v2f x2[4], xx2[4], wl2[4];
    float mu[4], w[4], inv_se[4], sig[4];
    float mean, prior_var, blender, omb, prior_p;
    float W0, W1, W2;   // iteration-invariant: sum_l wl*{1, x, x^2}
};

template <bool LAST>
__device__ __forceinline__ void em_iter(RowState& st, float* __restrict__ gout, int lane) {
    // Per-component quadratic in log2 domain, then deltas vs component 3:
    // lm_k - lm_3 = dA*x^2 + dB*x + dC (wave-uniform coefficients).
    float A[4], Bq[4], Cq[4];
#pragma unroll
    for (int k = 0; k < 4; ++k) {
        float is2 = st.inv_se[k] * st.inv_se[k];
        float lw2 = __log2f((st.w[k] + EPSf) * st.inv_se[k]);
        A[k] = (-0.5f * LOG2E) * is2;
        Bq[k] = (LOG2E * st.mu[k]) * is2;
        Cq[k] = fmaf((-0.5f * LOG2E) * (st.mu[k] * st.mu[k]), is2, lw2);
    }
    v2f dA[3], dB[3], dC[3];
#pragma unroll
    for (int k = 0; k < 3; ++k) {
        dA[k] = v2u(A[k] - A[3]);
        dB[k] = v2u(Bq[k] - Bq[3]);
        dC[k] = v2u(Cq[k] - Cq[3]);
    }

    v2f S0[3], S1[3], S2[3];
#pragma unroll
    for (int k = 0; k < 3; ++k) { S0[k] = v2u(0.f); S1[k] = v2u(0.f); S2[k] = v2u(0.f); }

#pragma unroll
    for (int p = 0; p < 4; ++p) {
        v2f r[3];
        v2f esum = v2u(1.f);   // component 3's ratio is exactly 1
#pragma unroll
        for (int k = 0; k < 3; ++k) {
            v2f lm = vfma(dA[k], st.xx2[p], vfma(dB[k], st.x2[p], dC[k]));
            r[k] = v2(fexp2(lm.x), fexp2(lm.y));
            esum += r[k];
        }
        v2f inv = v2(frcp(esum.x), frcp(esum.y));
        v2f wls = st.wl2[p] * inv;
        v2f wlsx = wls * st.x2[p];
        v2f wlsxx = wls * st.xx2[p];
#pragma unroll
        for (int k = 0; k < 3; ++k) {
            S0[k] = vfma(r[k], wls, S0[k]);
            S1[k] = vfma(r[k], wlsx, S1[k]);
            S2[k] = vfma(r[k], wlsxx, S2[k]);
        }
        if (LAST) {
            const int s0 = 256 * (p >> 1) + 4 * lane + 2 * (p & 1);
            *(float4*)(gout + (size_t)s0 * 4) =
                make_float4(r[0].x * inv.x, r[1].x * inv.x, r[2].x * inv.x, inv.x);
            *(float4*)(gout + (size_t)(s0 + 1) * 4) =
                make_float4(r[0].y * inv.y, r[1].y * inv.y, r[2].y * inv.y, inv.y);
        }
    }

    // Horizontal add of the float2 accumulators, then wave reduction.
    float T0[4], T1[4], T2[4];
#pragma unroll
    for (int k = 0; k < 3; ++k) {
        float t0 = S0[k].x + S0[k].y;
        float t1 = S1[k].x + S1[k].y;
        float t2 = S2[k].x + S2[k].y;
        wred3(t0, t1, t2);
        T0[k] = lane63(t0);
        T1[k] = lane63(t1);
        T2[k] = lane63(t2);
    }
    T0[3] = st.W0 - T0[0] - T0[1] - T0[2];
    T1[3] = st.W1 - T1[0] - T1[1] - T1[2];
    T2[3] = st.W2 - T2[0] - T2[1] - T2[2];

    // M-step (wave-uniform). Single-pass moments:
    // sum wg*(x-mu)^2 = S2 - 2*mu*S1 + mu^2*S0.
    float wn[4], wsum = 0.f;
#pragma unroll
    for (int k = 0; k < 4; ++k) {
        float sg = fmaxf(T0[k], EPSf);
        float rsg = frcp(sg);
        float dmu = T1[k] * rsg;
        float mun = fmaf(st.blender, dmu, st.omb * st.mean);
        float num = fmaf(mun * mun, T0[k], fmaf(-2.f * mun, T1[k], T2[k]));
        float dv = fmaxf(num * rsg, 0.f);
        float var = fmaf(st.blender, dv, st.omb * st.prior_var);
        float sgn = sqrtf(var + EPSf);
        st.mu[k] = mun;
        st.sig[k] = sgn;
        st.inv_se[k] = frcp(sgn + EPSf);
        wn[k] = sg + st.prior_p;
        wsum += wn[k];
    }
    float invws = frcp(wsum);
#pragma unroll
    for (int k = 0; k < 4; ++k) st.w[k] = wn[k] * invws;
}

__global__ __launch_bounds__(256, 4) void em_kernel(
    const float* __restrict__ windows,
    const float* __restrict__ centers,
    const float* __restrict__ scales,
    const float* __restrict__ iweights,
    const float* __restrict__ prior_p_param,
    const float* __restrict__ weights_param,
    const float* __restrict__ blend,
    const float* __restrict__ noise,
    float* __restrict__ out_g,
    float* __restrict__ out_w,
    float* __restrict__ out_mu,
    float* __restrict__ out_sigma)
{
    const int lane = threadIdx.x & 63;
    const int wv = threadIdx.x >> 6;
    const int b = blockIdx.x * 4 + wv;

    RowState st;
    const float* __restrict__ xr = windows + (size_t)b * Ln;
    const float4 q0 = *(const float4*)(xr + 4 * lane);
    const float4 q1 = *(const float4*)(xr + 256 + 4 * lane);
    st.x2[0] = v2(q0.x, q0.y); st.x2[1] = v2(q0.z, q0.w);
    st.x2[2] = v2(q1.x, q1.y); st.x2[3] = v2(q1.z, q1.w);

    const float4 e0 = *(const float4*)(weights_param + 4 * lane);
    const float4 e1 = *(const float4*)(weights_param + 256 + 4 * lane);
    st.wl2[0] = v2(__expf(e0.x), __expf(e0.y));
    st.wl2[1] = v2(__expf(e0.z), __expf(e0.w));
    st.wl2[2] = v2(__expf(e1.x), __expf(e1.y));
    st.wl2[3] = v2(__expf(e1.z), __expf(e1.w));

    // Row stats + iteration-invariant weighted totals.
    v2f sv = v2u(0.f), ssv = v2u(0.f), w0v = v2u(0.f), w1v = v2u(0.f), w2v = v2u(0.f);
#pragma unroll
    for (int p = 0; p < 4; ++p) {
        st.xx2[p] = st.x2[p] * st.x2[p];
        sv += st.x2[p];
        ssv += st.xx2[p];
        w0v += st.wl2[p];
        w1v = vfma(st.wl2[p], st.x2[p], w1v);
        w2v = vfma(st.wl2[p], st.xx2[p], w2v);
    }
    float s = sv.x + sv.y, ss = ssv.x + ssv.y, w0 = w0v.x + w0v.y;
    float w1 = w1v.x + w1v.y, w2 = w2v.x + w2v.y, junk = 0.f;
    wred3(s, ss, w0);
    wred3(w1, w2, junk);
    s = lane63(s);
    ss = lane63(ss);
    st.W0 = lane63(w0);
    st.W1 = lane63(w1);
    st.W2 = lane63(w2);

    st.mean = s * (1.0f / Ln);
    float var1 = fmaxf((ss - s * st.mean) * (1.0f / (Ln - 1)), 0.f);
    const float sd = sqrtf(var1);
    st.prior_var = var1;

    st.prior_p = 1.f / (1.f + __expf(-prior_p_param[0]));
    st.blender = 1.f / (1.f + __expf(-blend[0]));
    st.omb = 1.f - st.blender;

    const float4 nz = *(const float4*)(noise + (size_t)b * 4);
    const float nzv[4] = { nz.x, nz.y, nz.z, nz.w };

#pragma unroll
    for (int k = 0; k < 4; ++k) {
        st.mu[k] = fmaf(centers[k], sd, st.mean) + nzv[k] * sd * NOISEf;
        float sg0 = fabsf(scales[k]) * sd;
        st.sig[k] = sg0;
        st.w[k] = iweights[k];
        st.inv_se[k] = frcp(sg0 + EPSf);
    }

    float* gout = out_g + (size_t)b * Ln * Kn;
    for (int it = 0; it < NITER - 1; ++it)
        em_iter<false>(st, gout, lane);
    em_iter<true>(st, gout, lane);

    if (lane == 0) {
        *(float4*)(out_w     + (size_t)b * 4) = make_float4(st.w[0], st.w[1], st.w[2], st.w[3]);
        *(float4*)(out_mu    + (size_t)b * 4) = make_float4(st.mu[0], st.mu[1], st.mu[2], st.mu[3]);
        *(float4*)(out_sigma + (size_t)b * 4) = make_float4(st.sig[0], st.sig[1], st.sig[2], st.sig[3]);
    }
}

extern "C" void kernel_launch(void* const* d_in, const int* in_sizes, int n_in,
                              void* d_out, int out_size, void* d_ws, size_t ws_size,
                              hipStream_t stream) {
    const float* windows       = (const float*)d_in[0];
    const float* init_centers  = (const float*)d_in[1];
    const float* init_scales   = (const float*)d_in[2];
    const float* init_weights  = (const float*)d_in[3];
    const float* prior_p_param = (const float*)d_in[4];
    const float* weights_param = (const float*)d_in[5];
    const float* blend         = (const float*)d_in[6];
    const float* noise         = (const float*)d_in[7];

    float* out       = (float*)d_out;
    float* out_g     = out;                                    // [B, L, K]
    float* out_w     = out_g + (size_t)Bn * Ln * Kn;           // [B, K]
    float* out_mu    = out_w + (size_t)Bn * Kn;                // [B, K]
    float* out_sigma = out_mu + (size_t)Bn * Kn;               // [B, K]

    dim3 grid(Bn / 4);   // 4 waves per block, 1 wave per row
    dim3 block(256);
    hipLaunchKernelGGL(em_kernel, grid, block, 0, stream,
                       windows, init_centers, init_scales, init_weights,
                       prior_p_param, weights_param, blend, noise,
                       out_g, out_w, out_mu, out_sigma);
}

// Round 2
// 197.962 us; speedup vs baseline: 1.0762x; 1.0259x over previous
//
#include <hip/hip_runtime.h>
#include <math.h>

// NormalMixtureEM: B=16384 rows, L=512, K=4, 5 EM iters. One wave per row.
// R6 (uniform-section lane-parallelization; VALU-throughput-bound at ~86%):
//  - The per-iteration coefficient computation + M-step was wave-uniform work
//    replicated on 64 lanes and serial over 4 components (~25% of all VALU
//    cycles, 8 trans ops/iter). Now each lane owns component kk = lane&3:
//    one coefficient block + one M-step instance per lane (4x fewer ops,
//    trans 8 -> 4 per iter).
//  - Component-3 baseline via ds_swizzle(lane|3); the 9 wave-uniform inner
//    loop coefficients gathered to SGPRs via v_readlane (free broadcast as
//    SGPR operands of v_fma); weight normalization via xor-swizzle butterfly
//    within each 4-lane group.
//  - Inner loop back to scalar form: packed fp32 is issue-split on gfx950
//    (R5 measurement matched the split-rate prediction), and SGPR-sourced
//    scalar fmas avoid packed-pair-building movs.
//  - Kept from R5: ratio softmax vs component 3 (3 exp2 + 1 rcp / sample),
//    wred3 interleaved DPP reduction, float4 loads, iteration-invariant
//    W{0,1,2} totals deriving component 3's moments.

constexpr int Bn = 16384;
constexpr int Ln = 512;
constexpr int Kn = 4;
constexpr int NITER = 5;
constexpr float EPSf = 1e-8f;
constexpr float NOISEf = 0.01f;
constexpr float LOG2E = 1.4426950408889634f;

__device__ __forceinline__ float frcp(float v) { return __builtin_amdgcn_rcpf(v); }
__device__ __forceinline__ float fexp2(float v) { return __builtin_amdgcn_exp2f(v); }

// ds_swizzle (BitMode): src_lane = ((lane & and) | or) ^ xor, within 32-lane half.
// 0x7F  = and 0x1F, or 3, xor 0  -> lane|3  (component-3 slot of own 4-group)
// 0x041F = xor 1                  -> butterfly step 1 within 4-group
// 0x081F = xor 2                  -> butterfly step 2 within 4-group
template <int IMM>
__device__ __forceinline__ float swz(float v) {
    return __int_as_float(__builtin_amdgcn_ds_swizzle(__float_as_int(v), IMM));
}
__device__ __forceinline__ float rlane(float v, int l) {
    return __int_as_float(__builtin_amdgcn_readlane(__float_as_int(v), l));
}

// Three interleaved full-wave sums via DPP adds; total lands in lane 63.
// Round-robin keeps same-register DPP reads 3 instrs apart (hazard-free);
// s_nop 1 guards the asm boundaries.
#define WRED3_STEP(ctrl) \
    "v_add_f32_dpp %0, %0, %0 " ctrl " row_mask:0xf bank_mask:0xf bound_ctrl:0\n\t" \
    "v_add_f32_dpp %1, %1, %1 " ctrl " row_mask:0xf bank_mask:0xf bound_ctrl:0\n\t" \
    "v_add_f32_dpp %2, %2, %2 " ctrl " row_mask:0xf bank_mask:0xf bound_ctrl:0\n\t"

__device__ __forceinline__ void wred3(float& a, float& b, float& c) {
    asm volatile(
        "s_nop 1\n\t"
        WRED3_STEP("row_shr:1")
        WRED3_STEP("row_shr:2")
        WRED3_STEP("row_shr:4")
        WRED3_STEP("row_shr:8")
        WRED3_STEP("row_bcast:15")
        WRED3_STEP("row_bcast:31")
        "s_nop 1"
        : "+v"(a), "+v"(b), "+v"(c));
}

struct RowState {
    float x[8], xx[8], wl[8];
    float muk, wk, invsek, sigk;   // per-lane component k = lane&3
    float mean, prior_var, blender, prior_p;
    float bm, bv;                  // (1-blender)*mean, (1-blender)*prior_var
    float W0, W1, W2;              // iteration-invariant: sum_l wl*{1, x, x^2}
};

template <bool LAST>
__device__ __forceinline__ void em_iter(RowState& st, float* __restrict__ gout,
                                        int lane, int kk) {
    // Per-lane (k = kk) quadratic coefficients in log2 domain.
    float is2 = st.invsek * st.invsek;
    float lw2 = __log2f((st.wk + EPSf) * st.invsek);
    float Ak = (-0.5f * LOG2E) * is2;
    float Bk = (LOG2E * st.muk) * is2;
    float Ck = fmaf((-0.5f * LOG2E) * (st.muk * st.muk), is2, lw2);
    // Deltas vs component 3 (lane 3 of own 4-group); lane kk==3 holds 0.
    float dAl = Ak - swz<0x7F>(Ak);
    float dBl = Bk - swz<0x7F>(Bk);
    float dCl = Ck - swz<0x7F>(Ck);
    // Gather the 9 wave-uniform coefficients into SGPRs.
    float a0 = rlane(dAl, 0), a1 = rlane(dAl, 1), a2 = rlane(dAl, 2);
    float b0 = rlane(dBl, 0), b1 = rlane(dBl, 1), b2 = rlane(dBl, 2);
    float c0 = rlane(dCl, 0), c1 = rlane(dCl, 1), c2 = rlane(dCl, 2);

    float S00 = 0, S01 = 0, S02 = 0;
    float S10 = 0, S11 = 0, S12 = 0;
    float S20 = 0, S21 = 0, S22 = 0;
#pragma unroll
    for (int j = 0; j < 8; ++j) {
        float lm0 = fmaf(a0, st.xx[j], fmaf(b0, st.x[j], c0));
        float lm1 = fmaf(a1, st.xx[j], fmaf(b1, st.x[j], c1));
        float lm2 = fmaf(a2, st.xx[j], fmaf(b2, st.x[j], c2));
        float r0 = fexp2(lm0);
        float r1 = fexp2(lm1);
        float r2 = fexp2(lm2);
        float esum = 1.f + r0 + r1 + r2;   // component 3's ratio is exactly 1
        float inv = frcp(esum);
        float wls = st.wl[j] * inv;
        float wlsx = wls * st.x[j];
        float wlsxx = wls * st.xx[j];
        S00 = fmaf(r0, wls, S00); S10 = fmaf(r0, wlsx, S10); S20 = fmaf(r0, wlsxx, S20);
        S01 = fmaf(r1, wls, S01); S11 = fmaf(r1, wlsx, S11); S21 = fmaf(r1, wlsxx, S21);
        S02 = fmaf(r2, wls, S02); S12 = fmaf(r2, wlsx, S12); S22 = fmaf(r2, wlsxx, S22);
        if (LAST) {
            const int idx = (j < 4) ? (4 * lane + j) : (256 + 4 * lane + (j - 4));
            *(float4*)(gout + (size_t)idx * 4) =
                make_float4(r0 * inv, r1 * inv, r2 * inv, inv);
        }
    }

    // Wave-reduce the 9 moments; totals in lane 63 -> SGPRs.
    wred3(S00, S10, S20);
    wred3(S01, S11, S21);
    wred3(S02, S12, S22);
    float s00 = rlane(S00, 63), s10 = rlane(S10, 63), s20 = rlane(S20, 63);
    float s01 = rlane(S01, 63), s11 = rlane(S11, 63), s21 = rlane(S21, 63);
    float s02 = rlane(S02, 63), s12 = rlane(S12, 63), s22 = rlane(S22, 63);
    // Component 3 from iteration-invariant totals (sum_k g = 1).
    float d0 = st.W0 - s00 - s01 - s02;
    float d1 = st.W1 - s10 - s11 - s12;
    float d2 = st.W2 - s20 - s21 - s22;
    // Per-lane selection of this lane's component moments.
    float vT0 = (kk == 0) ? s00 : (kk == 1) ? s01 : (kk == 2) ? s02 : d0;
    float vT1 = (kk == 0) ? s10 : (kk == 1) ? s11 : (kk == 2) ? s12 : d1;
    float vT2 = (kk == 0) ? s20 : (kk == 1) ? s21 : (kk == 2) ? s22 : d2;

    // M-step, one component per lane. Single-pass moments:
    // sum wg*(x-mu)^2 = S2 - 2*mu*S1 + mu^2*S0.
    float sg = fmaxf(vT0, EPSf);
    float rsg = frcp(sg);
    float mun = fmaf(st.blender, vT1 * rsg, st.bm);
    float num = fmaf(mun * mun, vT0, fmaf(-2.f * mun, vT1, vT2));
    float dv = fmaxf(num * rsg, 0.f);
    float var = fmaf(st.blender, dv, st.bv);
    float sgn = sqrtf(var + EPSf);
    st.muk = mun;
    st.sigk = sgn;
    st.invsek = frcp(sgn + EPSf);
    float wn = sg + st.prior_p;
    // wsum over the 4-lane group via xor butterfly.
    float ws = wn + swz<0x041F>(wn);
    ws = ws + swz<0x081F>(ws);
    st.wk = wn * frcp(ws);
}

__global__ __launch_bounds__(256, 4) void em_kernel(
    const float* __restrict__ windows,
    const float* __restrict__ centers,
    const float* __restrict__ scales,
    const float* __restrict__ iweights,
    const float* __restrict__ prior_p_param,
    const float* __restrict__ weights_param,
    const float* __restrict__ blend,
    const float* __restrict__ noise,
    float* __restrict__ out_g,
    float* __restrict__ out_w,
    float* __restrict__ out_mu,
    float* __restrict__ out_sigma)
{
    const int lane = threadIdx.x & 63;
    const int kk = lane & 3;
    const int b = blockIdx.x * 4 + (threadIdx.x >> 6);

    RowState st;
    const float* __restrict__ xr = windows + (size_t)b * Ln;
    const float4 q0 = *(const float4*)(xr + 4 * lane);
    const float4 q1 = *(const float4*)(xr + 256 + 4 * lane);
    st.x[0] = q0.x; st.x[1] = q0.y; st.x[2] = q0.z; st.x[3] = q0.w;
    st.x[4] = q1.x; st.x[5] = q1.y; st.x[6] = q1.z; st.x[7] = q1.w;

    const float4 e0 = *(const float4*)(weights_param + 4 * lane);
    const float4 e1 = *(const float4*)(weights_param + 256 + 4 * lane);
    st.wl[0] = __expf(e0.x); st.wl[1] = __expf(e0.y);
    st.wl[2] = __expf(e0.z); st.wl[3] = __expf(e0.w);
    st.wl[4] = __expf(e1.x); st.wl[5] = __expf(e1.y);
    st.wl[6] = __expf(e1.z); st.wl[7] = __expf(e1.w);

    // Row stats + iteration-invariant weighted totals.
    float s = 0.f, ss = 0.f, w0 = 0.f, w1 = 0.f, w2 = 0.f;
#pragma unroll
    for (int j = 0; j < 8; ++j) {
        st.xx[j] = st.x[j] * st.x[j];
        s += st.x[j];
        ss += st.xx[j];
        w0 += st.wl[j];
        w1 = fmaf(st.wl[j], st.x[j], w1);
        w2 = fmaf(st.wl[j], st.xx[j], w2);
    }
    float junk = 0.f;
    wred3(s, ss, w0);
    wred3(w1, w2, junk);
    s = rlane(s, 63);
    ss = rlane(ss, 63);
    st.W0 = rlane(w0, 63);
    st.W1 = rlane(w1, 63);
    st.W2 = rlane(w2, 63);

    st.mean = s * (1.0f / Ln);
    float var1 = fmaxf((ss - s * st.mean) * (1.0f / (Ln - 1)), 0.f);
    const float sd = sqrtf(var1);
    st.prior_var = var1;

    st.prior_p = 1.f / (1.f + __expf(-prior_p_param[0]));
    st.blender = 1.f / (1.f + __expf(-blend[0]));
    const float omb = 1.f - st.blender;
    st.bm = omb * st.mean;
    st.bv = omb * st.prior_var;

    // Per-lane component init (k = kk).
    st.muk = fmaf(centers[kk], sd, st.mean) + noise[(size_t)b * 4 + kk] * sd * NOISEf;
    float sg0 = fabsf(scales[kk]) * sd;
    st.sigk = sg0;
    st.wk = iweights[kk];
    st.invsek = frcp(sg0 + EPSf);

    float* gout = out_g + (size_t)b * Ln * Kn;
    for (int it = 0; it < NITER - 1; ++it)
        em_iter<false>(st, gout, lane, kk);
    em_iter<true>(st, gout, lane, kk);

    if (lane < 4) {
        out_w[(size_t)b * 4 + lane]     = st.wk;
        out_mu[(size_t)b * 4 + lane]    = st.muk;
        out_sigma[(size_t)b * 4 + lane] = st.sigk;
    }
}

extern "C" void kernel_launch(void* const* d_in, const int* in_sizes, int n_in,
                              void* d_out, int out_size, void* d_ws, size_t ws_size,
                              hipStream_t stream) {
    const float* windows       = (const float*)d_in[0];
    const float* init_centers  = (const float*)d_in[1];
    const float* init_scales   = (const float*)d_in[2];
    const float* init_weights  = (const float*)d_in[3];
    const float* prior_p_param = (const float*)d_in[4];
    const float* weights_param = (const float*)d_in[5];
    const float* blend         = (const float*)d_in[6];
    const float* noise         = (const float*)d_in[7];

    float* out       = (float*)d_out;
    float* out_g     = out;                                    // [B, L, K]
    float* out_w     = out_g + (size_t)Bn * Ln * Kn;           // [B, K]
    float* out_mu    = out_w + (size_t)Bn * Kn;                // [B, K]
    float* out_sigma = out_mu + (size_t)Bn * Kn;               // [B, K]

    dim3 grid(Bn / 4);   // 4 waves per block, 1 wave per row
    dim3 block(256);
    hipLaunchKernelGGL(em_kernel, grid, block, 0, stream,
                       windows, init_centers, init_scales, init_weights,
                       prior_p_param, weights_param, blend, noise,
                       out_g, out_w, out_mu, out_sigma);
}